// Round 7
// baseline (1909.396 us; speedup 1.0000x reference)
//
#include <hip/hip_runtime.h>
#include <stdint.h>

// ============================================================================
// 24-qubit circuit simulator, 4 layers of (24 x 1q-expm gates + ZZ phases).
// State = 2^24 complex64 processed across 5 fused passes.
// STORAGE (runtime-selected on out_size):
//   SOA=1 (out_size == 2^24): re in d_out (2^24 f32), im in d_ws+WS_IM.
//          Final pass writes only scaled re to d_out (harness expects real part).
//   SOA=0 (out_size == 2^25): interleaved float2 in d_out.
// Each block: 8192 amps in 64KiB LDS, 32 amps/thread in registers,
// LDS transposes give every gate a thread-local (register) bit.
// Qubit q <-> flat-index bit (23-q).  Schedule:
//   A0 | B0+ZZ0+B1 | A1+ZZ1+A2 | B2+ZZ2+B3 | A3+ZZ3*(1/norm)
// ============================================================================

#define NQ 24
#define NSTATE (1u << NQ)

// ws layout (floats)
#define WS_NORM 0     // [0] accumulated |psi|^2
#define WS_U    8     // 96 matrices * 8 floats
#define WS_W    1024  // 4 layers * 32 floats: w[0..22], [23]=wrap, [24]=S
#define WS_IM   4096  // SOA imag plane: 2^24 floats (64 MiB), 16KiB offset

__device__ __forceinline__ int swz(int i) { return i ^ ((i >> 5) & 31); }

__device__ __forceinline__ float2 cmul(float2 a, float2 b) {
  return make_float2(a.x * b.x - a.y * b.y, a.x * b.y + a.y * b.x);
}

// apply 2x2 complex gate on local (register) bit P of c[32]
template <int P>
__device__ __forceinline__ void gate(float2 c[32], float2 u00, float2 u01,
                                     float2 u10, float2 u11) {
#pragma unroll
  for (int m = 0; m < 16; ++m) {
    const int r0 = ((m >> P) << (P + 1)) | (m & ((1 << P) - 1));
    const int r1 = r0 | (1 << P);
    float2 a = c[r0], b = c[r1];
    float2 n0, n1;
    n0.x = u00.x * a.x - u00.y * a.y + u01.x * b.x - u01.y * b.y;
    n0.y = u00.x * a.y + u00.y * a.x + u01.x * b.y + u01.y * b.x;
    n1.x = u10.x * a.x - u10.y * a.y + u11.x * b.x - u11.y * b.y;
    n1.y = u10.x * a.y + u10.y * a.x + u11.x * b.y + u11.y * b.x;
    c[r0] = n0;
    c[r1] = n1;
  }
}

// ---------------------------------------------------------------------------
// setup: 96 closed-form 2x2 expm's + per-layer ZZ weight tables + norm=0
// A = H - H^dag (anti-Herm), M = -iA = h0*I + h.sigma (Hermitian, h real)
// U = exp(iM) = e^{i h0} (cos t * I + i sin(t)/t * h.sigma), t = |h|
// ---------------------------------------------------------------------------
__global__ void setup_kernel(const float* __restrict__ Hre,
                             const float* __restrict__ Him,
                             const float* __restrict__ th1,
                             const float* __restrict__ th2, float* ws) {
  const int id = threadIdx.x;
  if (id < 96) {
    const int l = id / 24, q = id % 24;
    const float* hr = Hre + (l * 24 + q) * 4;  // H00,H01,H10,H11 (re)
    const float* hi = Him + (l * 24 + q) * 4;  // (im)
    const float h0 = hi[0] + hi[3];
    const float hz = hi[0] - hi[3];
    const float hx = hi[1] + hi[2];
    const float hy = hr[1] - hr[2];
    const float th = sqrtf(hx * hx + hy * hy + hz * hz);
    const float cth = cosf(th), sth = sinf(th);
    const float sc = (th > 1e-30f) ? sth / th : 1.0f;
    const float2 e = make_float2(cosf(h0), sinf(h0));
    const float2 u00 = cmul(e, make_float2(cth, sc * hz));
    const float2 u01 = cmul(e, make_float2(sc * hy, sc * hx));
    const float2 u10 = cmul(e, make_float2(-sc * hy, sc * hx));
    const float2 u11 = cmul(e, make_float2(cth, -sc * hz));
    float* p = ws + WS_U + (l * 24 + q) * 8;
    p[0] = u00.x; p[1] = u00.y; p[2] = u01.x; p[3] = u01.y;
    p[4] = u10.x; p[5] = u10.y; p[6] = u11.x; p[7] = u11.y;
  } else if (id < 100) {
    // phi(idx) = S - 2*(sum_k w[k]*y_k + wrap*(b0^b23)), y = idx ^ (idx>>1)
    // even pair i (qubits 2i,2i+1)   -> y bit 22-2i, weight theta1[l,i]
    // odd  pair i<11 (2i+1,2i+2)     -> y bit 21-2i, weight theta2[l,i]
    // odd  pair i=11 (23,0)          -> bits (0,23) wrap term
    const int l = id - 96;
    float w[23];
    for (int k = 0; k < 23; ++k) w[k] = 0.f;
    for (int i = 0; i < 12; ++i) w[22 - 2 * i] += th1[l * 12 + i];
    for (int i = 0; i < 11; ++i) w[21 - 2 * i] += th2[l * 12 + i];
    const float wrap = th2[l * 12 + 11];
    float S = wrap;
    for (int k = 0; k < 23; ++k) S += w[k];
    float* p = ws + WS_W + l * 32;
    for (int k = 0; k < 23; ++k) p[k] = w[k];
    p[23] = wrap;
    p[24] = S;
  } else if (id == 100) {
    ws[WS_NORM] = 0.f;
  }
}

// ---------------------------------------------------------------------------
// main pass kernel.
// TYPE 0 ("A"): tile = global bits 0..12 (qubits 11..23), block = bits 13..23
// TYPE 1 ("B"): tile bits {0,1} U {13..23} (qubits 0..10), block = bits 2..12
// MODE 0: load SoA input + norm partial, layer-l gates, store       (A only)
// MODE 1: layer-l gates, ZZ_l, layer-(l+1) gates, store
// MODE 2: layer-l gates, ZZ_l, scale re by 1/norm, store re only    (A only)
// Arrangements (register-resident bits of the 13-bit tile index):
//   L: bits 8..12   A: bits 0..4   B: bits 5..9
// ---------------------------------------------------------------------------
__device__ __forceinline__ uint32_t gIdxA(uint32_t blk, uint32_t ti) {
  return (blk << 13) | ti;
}
__device__ __forceinline__ uint32_t gIdxB(uint32_t blk, uint32_t ti) {
  return ((ti >> 2) << 13) | (blk << 2) | (ti & 3);
}

#define GATE(P, l, q)                                                      \
  {                                                                        \
    const float* up = wsU + ((l) * 24 + (q)) * 8;                          \
    gate<P>(c, make_float2(up[0], up[1]), make_float2(up[2], up[3]),       \
            make_float2(up[4], up[5]), make_float2(up[6], up[7]));         \
  }

#define XPOSE(CUR, NEW)                                   \
  __syncthreads();                                        \
  _Pragma("unroll") for (int r = 0; r < 32; ++r) {        \
    lds[swz(CUR)] = c[r];                                 \
  }                                                       \
  __syncthreads();                                        \
  _Pragma("unroll") for (int r = 0; r < 32; ++r) {        \
    c[r] = lds[swz(NEW)];                                 \
  }

#define IDX_L (t + (r << 8))
#define IDX_A ((t << 5) | r)
#define IDX_B ((t & 31) | (r << 5) | ((t >> 5) << 10))

template <int TYPE, int MODE, int SOA>
__global__ __launch_bounds__(256, 2) void qpass(
    const float* __restrict__ in_re, const float* __restrict__ in_im,
    float* __restrict__ sre_st, float* __restrict__ sim_st,
    float2* __restrict__ st, const float* __restrict__ ws, float* wsn,
    int layer) {
  __shared__ float2 lds[8192];
  const int t = threadIdx.x;
  const uint32_t blk = blockIdx.x;
  const float* wsU = ws + WS_U;
  float2 c[32];

  // ---- load (arrangement L; coalesced for TYPE 0, 32B segments TYPE 1) ----
#pragma unroll
  for (int r = 0; r < 32; ++r) {
    const uint32_t ti = IDX_L;
    const uint32_t g = (TYPE == 0) ? gIdxA(blk, ti) : gIdxB(blk, ti);
    if (MODE == 0)
      c[r] = make_float2(in_re[g], in_im[g]);
    else if (SOA)
      c[r] = make_float2(sre_st[g], sim_st[g]);
    else
      c[r] = st[g];
  }

  if (MODE == 0) {  // norm partial of the raw input
    float ss = 0.f;
#pragma unroll
    for (int r = 0; r < 32; ++r)
      ss = fmaf(c[r].x, c[r].x, fmaf(c[r].y, c[r].y, ss));
    for (int off = 32; off > 0; off >>= 1) ss += __shfl_down(ss, off);
    if ((t & 63) == 0) atomicAdd(wsn + WS_NORM, ss);
  }

  const int l0 = layer;
  // ---- first half: layer l0 gates ----
  if (TYPE == 0) { GATE(0, l0, 15) GATE(1, l0, 14) GATE(2, l0, 13) GATE(3, l0, 12) GATE(4, l0, 11) }
  else           { GATE(0, l0, 4)  GATE(1, l0, 3)  GATE(2, l0, 2)  GATE(3, l0, 1)  GATE(4, l0, 0) }
  XPOSE(IDX_L, IDX_A)
  if (TYPE == 0) { GATE(0, l0, 23) GATE(1, l0, 22) GATE(2, l0, 21) GATE(3, l0, 20) GATE(4, l0, 19) }
  else           { GATE(2, l0, 10) GATE(3, l0, 9)  GATE(4, l0, 8) }
  XPOSE(IDX_A, IDX_B)
  if (TYPE == 0) { GATE(0, l0, 18) GATE(1, l0, 17) GATE(2, l0, 16) }
  else           { GATE(0, l0, 7)  GATE(1, l0, 6)  GATE(2, l0, 5) }

  // ---- ZZ phase of layer l0 (diagonal; in arrangement B) ----
  if (MODE != 0) {
    const float* w = ws + WS_W + l0 * 32;
    const uint32_t ti0 = (t & 31) | ((t >> 5) << 10);  // IDX_B with r=0
    const uint32_t gbase = (TYPE == 0) ? gIdxA(blk, ti0) : gIdxB(blk, ti0);
    constexpr int KLO = (TYPE == 0) ? 4 : 15;
    constexpr int KHI = (TYPE == 0) ? 9 : 20;
    constexpr int SH = (TYPE == 0) ? 5 : 16;  // where r sits in global idx
    const uint32_t y0 = gbase ^ (gbase >> 1);
    float phi_b = w[24];
#pragma unroll
    for (int k = 0; k < 23; ++k)
      if (k < KLO || k > KHI) phi_b -= 2.f * w[k] * (float)((y0 >> k) & 1);
    phi_b -= 2.f * w[23] * (float)((gbase ^ (gbase >> 23)) & 1);
    // hoist the 6 r-varying weights into registers
    float wr[6];
#pragma unroll
    for (int k = 0; k < 6; ++k) wr[k] = w[KLO + k];
#pragma unroll
    for (int r = 0; r < 32; ++r) {
      const uint32_t g = gbase | ((uint32_t)r << SH);
      const uint32_t y = g ^ (g >> 1);
      float phi = phi_b;
#pragma unroll
      for (int k = 0; k < 6; ++k)
        phi -= 2.f * wr[k] * (float)((y >> (KLO + k)) & 1);
      float sn, cs;
      __sincosf(phi, &sn, &cs);
      c[r] = cmul(c[r], make_float2(cs, sn));
    }
  }

  if (MODE == 1) {
    // ---- second half: layer l0+1 gates, reverse arrangement walk ----
    const int l1 = layer + 1;
    if (TYPE == 0) { GATE(0, l1, 18) GATE(1, l1, 17) GATE(2, l1, 16) GATE(3, l1, 15) GATE(4, l1, 14) }
    else           { GATE(0, l1, 7)  GATE(1, l1, 6)  GATE(2, l1, 5) }
    XPOSE(IDX_B, IDX_A)
    if (TYPE == 0) { GATE(0, l1, 23) GATE(1, l1, 22) GATE(2, l1, 21) GATE(3, l1, 20) GATE(4, l1, 19) }
    else           { GATE(2, l1, 10) GATE(3, l1, 9)  GATE(4, l1, 8) }
    XPOSE(IDX_A, IDX_L)
    if (TYPE == 0) { GATE(2, l1, 13) GATE(3, l1, 12) GATE(4, l1, 11) }
    else           { GATE(0, l1, 4)  GATE(1, l1, 3)  GATE(2, l1, 2)  GATE(3, l1, 1)  GATE(4, l1, 0) }
    // store from arrangement L (coalesced)
#pragma unroll
    for (int r = 0; r < 32; ++r) {
      const uint32_t ti = IDX_L;
      const uint32_t g = (TYPE == 0) ? gIdxA(blk, ti) : gIdxB(blk, ti);
      if (SOA) { sre_st[g] = c[r].x; sim_st[g] = c[r].y; }
      else st[g] = c[r];
    }
  } else {
    // MODE 0 / 2: store from arrangement B.  MODE 2 + SOA: re only.
    float scale = 1.f;
    if (MODE == 2) scale = rsqrtf(wsn[WS_NORM]);
#pragma unroll
    for (int r = 0; r < 32; ++r) {
      const uint32_t ti = IDX_B;
      const uint32_t g = (TYPE == 0) ? gIdxA(blk, ti) : gIdxB(blk, ti);
      float2 v = c[r];
      v.x *= scale;
      v.y *= scale;
      if (SOA) {
        sre_st[g] = v.x;
        if (MODE != 2) sim_st[g] = v.y;
      } else {
        st[g] = v;
      }
    }
  }
}

// ---------------------------------------------------------------------------
extern "C" void kernel_launch(void* const* d_in, const int* in_sizes, int n_in,
                              void* d_out, int out_size, void* d_ws,
                              size_t ws_size, hipStream_t stream) {
  (void)in_sizes; (void)n_in; (void)ws_size;
  const float* sre = (const float*)d_in[0];
  const float* sim = (const float*)d_in[1];
  const float* Hre = (const float*)d_in[2];
  const float* Him = (const float*)d_in[3];
  const float* th1 = (const float*)d_in[4];
  const float* th2 = (const float*)d_in[5];
  float* ws = (float*)d_ws;
  float* sre_st = (float*)d_out;        // SOA: re plane lives in d_out
  float* sim_st = ws + WS_IM;           // SOA: im plane in workspace
  float2* st = (float2*)d_out;          // AoS fallback (out_size == 2^25)

  hipLaunchKernelGGL(setup_kernel, dim3(1), dim3(128), 0, stream, Hre, Him,
                     th1, th2, ws);
  // Ping-pong schedule: A0 | B0+ZZ0+B1 | A1+ZZ1+A2 | B2+ZZ2+B3 | A3+ZZ3*scale
  const bool soa = (out_size <= (1 << 24));  // d_out = 2^24 floats (real part)
  if (soa) {
    hipLaunchKernelGGL((qpass<0, 0, 1>), dim3(2048), dim3(256), 0, stream,
                       sre, sim, sre_st, sim_st, st, ws, ws, 0);
    hipLaunchKernelGGL((qpass<1, 1, 1>), dim3(2048), dim3(256), 0, stream,
                       sre, sim, sre_st, sim_st, st, ws, ws, 0);
    hipLaunchKernelGGL((qpass<0, 1, 1>), dim3(2048), dim3(256), 0, stream,
                       sre, sim, sre_st, sim_st, st, ws, ws, 1);
    hipLaunchKernelGGL((qpass<1, 1, 1>), dim3(2048), dim3(256), 0, stream,
                       sre, sim, sre_st, sim_st, st, ws, ws, 2);
    hipLaunchKernelGGL((qpass<0, 2, 1>), dim3(2048), dim3(256), 0, stream,
                       sre, sim, sre_st, sim_st, st, ws, ws, 3);
  } else {
    hipLaunchKernelGGL((qpass<0, 0, 0>), dim3(2048), dim3(256), 0, stream,
                       sre, sim, sre_st, sim_st, st, ws, ws, 0);
    hipLaunchKernelGGL((qpass<1, 1, 0>), dim3(2048), dim3(256), 0, stream,
                       sre, sim, sre_st, sim_st, st, ws, ws, 0);
    hipLaunchKernelGGL((qpass<0, 1, 0>), dim3(2048), dim3(256), 0, stream,
                       sre, sim, sre_st, sim_st, st, ws, ws, 1);
    hipLaunchKernelGGL((qpass<1, 1, 0>), dim3(2048), dim3(256), 0, stream,
                       sre, sim, sre_st, sim_st, st, ws, ws, 2);
    hipLaunchKernelGGL((qpass<0, 2, 0>), dim3(2048), dim3(256), 0, stream,
                       sre, sim, sre_st, sim_st, st, ws, ws, 3);
  }
}